// Round 1
// baseline (343.326 us; speedup 1.0000x reference)
//
#include <hip/hip_runtime.h>
#include <hip/hip_bf16.h>

// GPT2 attention, B=2 S=2048 E=1024 H=16 hd=64.
// Pipeline: cast X -> bf16; transpose weights -> bf16 [N][K]; MFMA GEMM qkv;
// MFMA flash attention; MFMA GEMM proj -> fp32 out.

typedef __attribute__((ext_vector_type(4))) float f32x4;
typedef __attribute__((ext_vector_type(8))) short short8;

__device__ __forceinline__ unsigned short f2bf(float f) {
    union { float f; unsigned int u; } v; v.f = f;
    unsigned int r = v.u + 0x7FFFu + ((v.u >> 16) & 1u);
    return (unsigned short)(r >> 16);
}

// ---------------------------------------------------------------- cast fp32 -> bf16
__global__ __launch_bounds__(256) void cast_f32_bf16(
    const float* __restrict__ in, unsigned short* __restrict__ out, int n) {
    int i = (blockIdx.x * 256 + threadIdx.x) * 4;
    if (i >= n) return;
    float4 v = *(const float4*)(in + i);
    ushort4 o;
    o.x = f2bf(v.x); o.y = f2bf(v.y); o.z = f2bf(v.z); o.w = f2bf(v.w);
    *(ushort4*)(out + i) = o;
}

// ---------------------------------------------------------------- W [K][N] fp32 -> Wt [N][K] bf16
__global__ __launch_bounds__(256) void transpose_w(
    const float* __restrict__ W, unsigned short* __restrict__ Wt, int K, int N) {
    __shared__ float tile[32][33];
    int k0 = blockIdx.y * 32, n0 = blockIdx.x * 32;
    int t = threadIdx.x;
    int r = t >> 3, c = (t & 7) * 4;
    float4 v = *(const float4*)&W[(size_t)(k0 + r) * N + n0 + c];
    tile[r][c] = v.x; tile[r][c + 1] = v.y; tile[r][c + 2] = v.z; tile[r][c + 3] = v.w;
    __syncthreads();
    int n = t >> 3; int kk = (t & 7) * 4;
    ushort4 o;
    o.x = f2bf(tile[kk + 0][n]);
    o.y = f2bf(tile[kk + 1][n]);
    o.z = f2bf(tile[kk + 2][n]);
    o.w = f2bf(tile[kk + 3][n]);
    *(ushort4*)&Wt[(size_t)(n0 + n) * K + k0 + kk] = o;
}

// ---------------------------------------------------------------- C[M][N] = A[M][K] @ Bt[N][K]^T + bias
// A,Bt bf16; C fp32 or bf16. 64x64 tile, 4 waves, 16x16x32 MFMA.
template <bool OUT_BF16>
__global__ __launch_bounds__(256) void gemm_bt(
    const unsigned short* __restrict__ A,
    const unsigned short* __restrict__ Bt,
    const float* __restrict__ bias,
    void* __restrict__ C, int M, int N, int K) {
    __shared__ unsigned short As[64][40];
    __shared__ unsigned short Bs[64][40];
    int t = threadIdx.x;
    int wave = t >> 6, lane = t & 63;
    int l15 = lane & 15, quad = lane >> 4;
    int m0 = blockIdx.y * 64, n0 = blockIdx.x * 64;
    int row = t >> 2, cchunk = (t & 3) * 8;
    const unsigned short* Aptr = A + (size_t)(m0 + row) * K + cchunk;
    const unsigned short* Bptr = Bt + (size_t)(n0 + row) * K + cchunk;
    f32x4 acc[4] = {};
    for (int k0 = 0; k0 < K; k0 += 32) {
        *(uint4*)&As[row][cchunk] = *(const uint4*)(Aptr + k0);
        *(uint4*)&Bs[row][cchunk] = *(const uint4*)(Bptr + k0);
        __syncthreads();
        short8 a = *(const short8*)&As[wave * 16 + l15][quad * 8];
#pragma unroll
        for (int nt = 0; nt < 4; ++nt) {
            short8 b = *(const short8*)&Bs[nt * 16 + l15][quad * 8];
            acc[nt] = __builtin_amdgcn_mfma_f32_16x16x32_bf16(a, b, acc[nt], 0, 0, 0);
        }
        __syncthreads();
    }
    int mrow = m0 + wave * 16 + quad * 4;
#pragma unroll
    for (int nt = 0; nt < 4; ++nt) {
        int col = n0 + nt * 16 + l15;
        float bv = bias[col];
#pragma unroll
        for (int r = 0; r < 4; ++r) {
            float v = acc[nt][r] + bv;
            if (OUT_BF16)
                ((unsigned short*)C)[(size_t)(mrow + r) * N + col] = f2bf(v);
            else
                ((float*)C)[(size_t)(mrow + r) * N + col] = v;
        }
    }
}

// ---------------------------------------------------------------- flash attention
// qkv bf16 [B][S][3E], head-interleaved: head h occupies cols [h*192, h*192+192) = [q|k|v].
// out bf16 [B][S][E], e = h*64 + d. One block = (b, h, 64-row q-tile). 256 threads / 4 waves.
__global__ __launch_bounds__(256) void attn_kernel(
    const unsigned short* __restrict__ qkv,
    unsigned short* __restrict__ out, int B, int S) {
    const int E = 1024, QKVW = 3072;
    __shared__ unsigned short Ks[64][72];   // K[kv][d]
    __shared__ unsigned short Vts[64][72];  // V^T[d][kv]
    __shared__ unsigned short Ps[4][16][72];// per-wave P[q][kv]
    int t = threadIdx.x, wave = t >> 6, lane = t & 63;
    int l15 = lane & 15, quad = lane >> 4;
    int idx = blockIdx.x;
    int qt = 31 - (idx & 31);        // descending trip count for load balance
    int bh = idx >> 5;
    int b = bh >> 4, h = bh & 15;
    const unsigned short* base = qkv + (size_t)b * S * QKVW + h * 192;

    // hoist Q fragments (A-operand): lane holds Q[q=wave*16+l15][d=km*32+quad*8 ..+8]
    short8 qf[2];
    int qrow = qt * 64 + wave * 16 + l15;
#pragma unroll
    for (int km = 0; km < 2; ++km)
        qf[km] = *(const short8*)(base + (size_t)qrow * QKVW + km * 32 + quad * 8);

    f32x4 o[4] = {};
    float mrun[4], lrun[4];
#pragma unroll
    for (int r = 0; r < 4; ++r) { mrun[r] = -1e30f; lrun[r] = 0.f; }

    int srow8 = t >> 3, chunk = t & 7;
    for (int kt = 0; kt <= qt; ++kt) {
        // stage K tile and transposed V tile
#pragma unroll
        for (int i = 0; i < 2; ++i) {
            int sr = i * 32 + srow8;
            const unsigned short* rp = base + (size_t)(kt * 64 + sr) * QKVW;
            *(uint4*)&Ks[sr][chunk * 8] = *(const uint4*)(rp + 64 + chunk * 8);
            uint4 vv = *(const uint4*)(rp + 128 + chunk * 8);
            const unsigned short* ve = (const unsigned short*)&vv;
#pragma unroll
            for (int j = 0; j < 8; ++j) Vts[chunk * 8 + j][sr] = ve[j];
        }
        __syncthreads();

        // S = Q K^T
        f32x4 s[4] = {};
#pragma unroll
        for (int km = 0; km < 2; ++km) {
#pragma unroll
            for (int nt = 0; nt < 4; ++nt) {
                short8 kf = *(const short8*)&Ks[nt * 16 + l15][km * 32 + quad * 8];
                s[nt] = __builtin_amdgcn_mfma_f32_16x16x32_bf16(qf[km], kf, s[nt], 0, 0, 0);
            }
        }
        // scale + causal mask (diagonal tile only)
        bool diag = (kt == qt);
#pragma unroll
        for (int nt = 0; nt < 4; ++nt)
#pragma unroll
            for (int r = 0; r < 4; ++r) {
                float v = s[nt][r] * 0.125f;
                if (diag) {
                    int rr = wave * 16 + quad * 4 + r;
                    int cc = nt * 16 + l15;
                    if (cc > rr) v = -10000.0f;
                }
                s[nt][r] = v;
            }
        // row max across 4 ntiles + 16 lanes of quad group
        float mt[4];
#pragma unroll
        for (int r = 0; r < 4; ++r) {
            float v = fmaxf(fmaxf(s[0][r], s[1][r]), fmaxf(s[2][r], s[3][r]));
#pragma unroll
            for (int off = 1; off < 16; off <<= 1)
                v = fmaxf(v, __shfl_xor(v, off, 64));
            mt[r] = v;
        }
        float alpha[4];
#pragma unroll
        for (int r = 0; r < 4; ++r) {
            float mnew = fmaxf(mrun[r], mt[r]);
            alpha[r] = __expf(mrun[r] - mnew);
            mrun[r] = mnew;
        }
        float lt[4] = {0.f, 0.f, 0.f, 0.f};
#pragma unroll
        for (int nt = 0; nt < 4; ++nt)
#pragma unroll
            for (int r = 0; r < 4; ++r) {
                float p = __expf(s[nt][r] - mrun[r]);
                s[nt][r] = p;
                lt[r] += p;
            }
#pragma unroll
        for (int r = 0; r < 4; ++r) {
            float v = lt[r];
#pragma unroll
            for (int off = 1; off < 16; off <<= 1)
                v += __shfl_xor(v, off, 64);
            lrun[r] = lrun[r] * alpha[r] + v;
        }
#pragma unroll
        for (int nt = 0; nt < 4; ++nt)
#pragma unroll
            for (int r = 0; r < 4; ++r) o[nt][r] *= alpha[r];
        // P -> LDS (C-layout -> A-layout round trip)
#pragma unroll
        for (int nt = 0; nt < 4; ++nt)
#pragma unroll
            for (int r = 0; r < 4; ++r)
                Ps[wave][quad * 4 + r][nt * 16 + l15] = f2bf(s[nt][r]);
        __syncthreads();
        // O += P V
#pragma unroll
        for (int km = 0; km < 2; ++km) {
            short8 pf = *(const short8*)&Ps[wave][l15][km * 32 + quad * 8];
#pragma unroll
            for (int nt = 0; nt < 4; ++nt) {
                short8 vf = *(const short8*)&Vts[nt * 16 + l15][km * 32 + quad * 8];
                o[nt] = __builtin_amdgcn_mfma_f32_16x16x32_bf16(pf, vf, o[nt], 0, 0, 0);
            }
        }
        __syncthreads();
    }
    // epilogue: out[b][s][h*64 + d] = o / l
    unsigned short* ob = out + (size_t)b * S * E + h * 64;
#pragma unroll
    for (int nt = 0; nt < 4; ++nt)
#pragma unroll
        for (int r = 0; r < 4; ++r) {
            int srow = qt * 64 + wave * 16 + quad * 4 + r;
            float v = o[nt][r] / lrun[r];
            ob[(size_t)srow * E + nt * 16 + l15] = f2bf(v);
        }
}

// ----------------------------------------------------------------
extern "C" void kernel_launch(void* const* d_in, const int* in_sizes, int n_in,
                              void* d_out, int out_size, void* d_ws, size_t ws_size,
                              hipStream_t stream) {
    const float* hs     = (const float*)d_in[0]; // [2,2048,1024]
    const float* W_attn = (const float*)d_in[1]; // [1024,3072]
    const float* b_attn = (const float*)d_in[2]; // [3072]
    const float* W_proj = (const float*)d_in[3]; // [1024,1024]
    const float* b_proj = (const float*)d_in[4]; // [1024]
    float* out = (float*)d_out;                  // [2,2048,1024]

    const int B = 2, S = 2048, E = 1024;
    const int M = B * S;        // 4096
    const int N3 = 3 * E;       // 3072

    unsigned short* Xb  = (unsigned short*)d_ws;          // M*E bf16
    unsigned short* WaT = Xb + (size_t)M * E;             // N3*E
    unsigned short* WpT = WaT + (size_t)N3 * E;           // E*E
    unsigned short* qkv = WpT + (size_t)E * E;            // M*N3
    unsigned short* ao  = qkv + (size_t)M * N3;           // M*E

    cast_f32_bf16<<<(M * E) / 1024, 256, 0, stream>>>(hs, Xb, M * E);
    transpose_w<<<dim3(N3 / 32, E / 32), 256, 0, stream>>>(W_attn, WaT, E, N3);
    transpose_w<<<dim3(E / 32, E / 32), 256, 0, stream>>>(W_proj, WpT, E, E);

    gemm_bt<true><<<dim3(N3 / 64, M / 64), 256, 0, stream>>>(Xb, WaT, b_attn, qkv, M, N3, E);

    attn_kernel<<<dim3(B * 16 * (S / 64)), 256, 0, stream>>>(qkv, ao, B, S);

    gemm_bt<false><<<dim3(E / 64, M / 64), 256, 0, stream>>>(ao, WpT, b_proj, out, M, E, E);
}

// Round 2
// 217.561 us; speedup vs baseline: 1.5781x; 1.5781x over previous
//
#include <hip/hip_runtime.h>
#include <hip/hip_bf16.h>

// GPT2 attention, B=2 S=2048 E=1024 H=16 hd=64.
// cast X->bf16; transpose weights->bf16 [N][K]; m97-style MFMA GEMM qkv
// (V written transposed to Vt[b][h][d][s]); paired-tile flash attention with
// DPP reductions; m97-style MFMA GEMM proj -> fp32 out.

typedef __attribute__((ext_vector_type(4))) float f32x4;
typedef __attribute__((ext_vector_type(8))) short short8;

#define AS1 __attribute__((address_space(1)))
#define AS3 __attribute__((address_space(3)))

__device__ __forceinline__ void load_lds16(const void* g, void* l) {
    __builtin_amdgcn_global_load_lds((const AS1 void*)g, (AS3 void*)l, 16, 0, 0);
}

__device__ __forceinline__ unsigned short f2bf(float f) {
    union { float f; unsigned int u; } v; v.f = f;
    unsigned int r = v.u + 0x7FFFu + ((v.u >> 16) & 1u);
    return (unsigned short)(r >> 16);
}

template <int CTRL>
__device__ __forceinline__ float rot_add(float x) {
    int r = __builtin_amdgcn_update_dpp(0, __builtin_bit_cast(int, x), CTRL, 0xF, 0xF, false);
    return x + __builtin_bit_cast(float, r);
}
template <int CTRL>
__device__ __forceinline__ float rot_max(float x) {
    int r = __builtin_amdgcn_update_dpp(0, __builtin_bit_cast(int, x), CTRL, 0xF, 0xF, false);
    return fmaxf(x, __builtin_bit_cast(float, r));
}

// ---------------------------------------------------------------- cast fp32 -> bf16
__global__ __launch_bounds__(256) void cast_f32_bf16(
    const float* __restrict__ in, unsigned short* __restrict__ out, int n) {
    int i = (blockIdx.x * 256 + threadIdx.x) * 4;
    if (i >= n) return;
    float4 v = *(const float4*)(in + i);
    ushort4 o;
    o.x = f2bf(v.x); o.y = f2bf(v.y); o.z = f2bf(v.z); o.w = f2bf(v.w);
    *(ushort4*)(out + i) = o;
}

// ---------------------------------------------------------------- W [K][N] fp32 -> Wt [N][K] bf16
__global__ __launch_bounds__(256) void transpose_w(
    const float* __restrict__ W, unsigned short* __restrict__ Wt, int K, int N) {
    __shared__ float tile[32][33];
    int k0 = blockIdx.y * 32, n0 = blockIdx.x * 32;
    int t = threadIdx.x;
    int r = t >> 3, c = (t & 7) * 4;
    float4 v = *(const float4*)&W[(size_t)(k0 + r) * N + n0 + c];
    tile[r][c] = v.x; tile[r][c + 1] = v.y; tile[r][c + 2] = v.z; tile[r][c + 3] = v.w;
    __syncthreads();
    int n = t >> 3; int kk = (t & 7) * 4;
    ushort4 o;
    o.x = f2bf(tile[kk + 0][n]);
    o.y = f2bf(tile[kk + 1][n]);
    o.z = f2bf(tile[kk + 2][n]);
    o.w = f2bf(tile[kk + 3][n]);
    *(ushort4*)&Wt[(size_t)(n0 + n) * K + k0 + kk] = o;
}

// ---------------------------------------------------------------- m97-style GEMM
// C[M][N] = A[M][K] @ Bt[N][K]^T + bias. 128x128 tile, BK=32, 4 waves 2x2,
// global_load_lds width-16 staging (unpadded lane-ordered LDS).
// MODE 0: fp32 C. MODE 1: qkv split -> qk[s][h*128 + (q|k)] bf16, V -> Vt[b][h][d][s].
template <int MODE>
__global__ __launch_bounds__(256) void gemm128(
    const unsigned short* __restrict__ A,
    const unsigned short* __restrict__ Bt,
    const float* __restrict__ bias,
    void* __restrict__ C, unsigned short* __restrict__ Vt,
    int M, int N, int K) {
    __shared__ unsigned short As[128 * 32];
    __shared__ unsigned short Bs[128 * 32];
    const int t = threadIdx.x, wave = t >> 6, lane = t & 63;
    const int l15 = lane & 15, quad = lane >> 4;
    const int m0 = blockIdx.y * 128, n0 = blockIdx.x * 128;
    // staging: lane i of wave covers row (w*32 + j*16 + i/4), 16B chunk (i&3)
    const int srow = wave * 32 + (lane >> 2);
    const int sch = (lane & 3) * 8;
    const unsigned short* Ag = A + (size_t)(m0 + srow) * K + sch;
    const unsigned short* Bg = Bt + (size_t)(n0 + srow) * K + sch;
    unsigned short* AsW = &As[wave * 32 * 32];   // wave-uniform; HW adds lane*16B
    unsigned short* BsW = &Bs[wave * 32 * 32];
    const int wm = (wave >> 1) * 64, wn = (wave & 1) * 64;
    f32x4 acc[4][4] = {};
    for (int k0 = 0; k0 < K; k0 += 32) {
        load_lds16(Ag + k0, AsW);
        load_lds16(Ag + k0 + (size_t)16 * K, AsW + 16 * 32);
        load_lds16(Bg + k0, BsW);
        load_lds16(Bg + k0 + (size_t)16 * K, BsW + 16 * 32);
        __syncthreads();
        short8 af[4], bf[4];
#pragma unroll
        for (int i = 0; i < 4; ++i) {
            af[i] = *(const short8*)&As[(wm + i * 16 + l15) * 32 + quad * 8];
            bf[i] = *(const short8*)&Bs[(wn + i * 16 + l15) * 32 + quad * 8];
        }
#pragma unroll
        for (int mt = 0; mt < 4; ++mt)
#pragma unroll
            for (int nt = 0; nt < 4; ++nt)
                acc[mt][nt] = __builtin_amdgcn_mfma_f32_16x16x32_bf16(af[mt], bf[nt], acc[mt][nt], 0, 0, 0);
        __syncthreads();
    }
#pragma unroll
    for (int mt = 0; mt < 4; ++mt) {
        int mrow = m0 + wm + mt * 16 + quad * 4;
#pragma unroll
        for (int nt = 0; nt < 4; ++nt) {
            int col = n0 + wn + nt * 16 + l15;
            float bv = bias[col];
            if (MODE == 0) {
                float* Cf = (float*)C;
#pragma unroll
                for (int r = 0; r < 4; ++r)
                    Cf[(size_t)(mrow + r) * N + col] = acc[mt][nt][r] + bv;
            } else {
                int h = col / 192;
                int j = col - h * 192;
                if (j < 128) {  // Q or K -> qk buffer (both land at h*128 + j)
                    unsigned short* qk = (unsigned short*)C;
#pragma unroll
                    for (int r = 0; r < 4; ++r)
                        qk[(size_t)(mrow + r) * 2048 + h * 128 + j] = f2bf(acc[mt][nt][r] + bv);
                } else {        // V -> Vt[b][h][d][s], 4 consecutive s packed
                    int b = mrow >> 11, s0 = mrow & 2047;
                    int d = j - 128;
                    ushort4 pk;
                    pk.x = f2bf(acc[mt][nt][0] + bv);
                    pk.y = f2bf(acc[mt][nt][1] + bv);
                    pk.z = f2bf(acc[mt][nt][2] + bv);
                    pk.w = f2bf(acc[mt][nt][3] + bv);
                    *(ushort4*)&Vt[((size_t)(b * 16 + h) * 64 + d) * 2048 + s0] = pk;
                }
            }
        }
    }
}

// ---------------------------------------------------------------- flash attention tile
__device__ __forceinline__ void attn_tile(
    f32x4 (&o)[4], float (&mrun)[4], float (&lrun)[4],
    const short8 (&qf)[2],
    const unsigned short (*Ks)[72], const unsigned short (*Vts)[72],
    unsigned short (*Psw)[72],
    bool diag, int wave, int l15, int quad) {
    f32x4 s[4] = {};
#pragma unroll
    for (int km = 0; km < 2; ++km)
#pragma unroll
        for (int nt = 0; nt < 4; ++nt) {
            short8 kf = *(const short8*)&Ks[nt * 16 + l15][km * 32 + quad * 8];
            s[nt] = __builtin_amdgcn_mfma_f32_16x16x32_bf16(qf[km], kf, s[nt], 0, 0, 0);
        }
#pragma unroll
    for (int nt = 0; nt < 4; ++nt)
#pragma unroll
        for (int r = 0; r < 4; ++r) {
            float v = s[nt][r] * 0.125f;
            if (diag && (nt * 16 + l15 > wave * 16 + quad * 4 + r)) v = -10000.0f;
            s[nt][r] = v;
        }
#pragma unroll
    for (int r = 0; r < 4; ++r) {
        float v = fmaxf(fmaxf(s[0][r], s[1][r]), fmaxf(s[2][r], s[3][r]));
        v = rot_max<0x121>(v); v = rot_max<0x122>(v);
        v = rot_max<0x124>(v); v = rot_max<0x128>(v);
        float mnew = fmaxf(mrun[r], v);
        float alpha = __expf(mrun[r] - mnew);
        mrun[r] = mnew;
        float lt = 0.f;
#pragma unroll
        for (int nt = 0; nt < 4; ++nt) {
            float pv = __expf(s[nt][r] - mnew);
            s[nt][r] = pv;
            lt += pv;
        }
        lt = rot_add<0x121>(lt); lt = rot_add<0x122>(lt);
        lt = rot_add<0x124>(lt); lt = rot_add<0x128>(lt);
        lrun[r] = lrun[r] * alpha + lt;
#pragma unroll
        for (int nt = 0; nt < 4; ++nt) o[nt][r] *= alpha;
    }
    // P: C-layout -> A-layout via wave-private LDS (per-wave in-order, no barrier)
#pragma unroll
    for (int nt = 0; nt < 4; ++nt)
#pragma unroll
        for (int r = 0; r < 4; ++r)
            Psw[quad * 4 + r][nt * 16 + l15] = f2bf(s[nt][r]);
#pragma unroll
    for (int km = 0; km < 2; ++km) {
        short8 pf = *(const short8*)&Psw[l15][km * 32 + quad * 8];
#pragma unroll
        for (int nt = 0; nt < 4; ++nt) {
            short8 vf = *(const short8*)&Vts[nt * 16 + l15][km * 32 + quad * 8];
            o[nt] = __builtin_amdgcn_mfma_f32_16x16x32_bf16(pf, vf, o[nt], 0, 0, 0);
        }
    }
}

__device__ __forceinline__ void attn_store(
    unsigned short* ob, const f32x4 (&o)[4], const float (&l)[4],
    int qtile, int wave, int l15, int quad) {
#pragma unroll
    for (int r = 0; r < 4; ++r) {
        float inv = 1.0f / l[r];
        int srow = qtile * 64 + wave * 16 + quad * 4 + r;
#pragma unroll
        for (int nt = 0; nt < 4; ++nt)
            ob[(size_t)srow * 1024 + nt * 16 + l15] = f2bf(o[nt][r] * inv);
    }
}

// One block = (b, h, tile-pair p): q-tiles p and 31-p -> constant 33 tile-computes.
// K/V staged once per kt, shared by both q-tiles.
__global__ __launch_bounds__(256) void attn2(
    const unsigned short* __restrict__ qk,   // [B*S][2048], head h: [h*128+q | +64 k]
    const unsigned short* __restrict__ Vt,   // [B*H][64][2048]
    unsigned short* __restrict__ out) {      // [B*S][1024]
    const int S = 2048;
    __shared__ unsigned short Ks[64][72];
    __shared__ unsigned short Vts[64][72];
    __shared__ unsigned short Ps[4][16][72];
    int t = threadIdx.x, wave = t >> 6, lane = t & 63;
    int l15 = lane & 15, quad = lane >> 4;
    int bid = blockIdx.x;
    int p = bid & 15, bh = bid >> 4;
    int b = bh >> 4, h = bh & 15;
    int qlo = p, qhi = 31 - p;
    const unsigned short* qkb = qk + (size_t)b * S * 2048 + h * 128;
    const unsigned short* vtb = Vt + (size_t)bh * 64 * 2048;

    short8 qfl[2], qfh[2];
    {
        int rl = qlo * 64 + wave * 16 + l15;
        int rh = qhi * 64 + wave * 16 + l15;
#pragma unroll
        for (int km = 0; km < 2; ++km) {
            qfl[km] = *(const short8*)(qkb + (size_t)rl * 2048 + km * 32 + quad * 8);
            qfh[km] = *(const short8*)(qkb + (size_t)rh * 2048 + km * 32 + quad * 8);
        }
    }
    f32x4 ol[4] = {}, oh[4] = {};
    float ml[4], ll[4], mh[4], lh[4];
#pragma unroll
    for (int r = 0; r < 4; ++r) { ml[r] = mh[r] = -1e30f; ll[r] = lh[r] = 0.f; }

    int srow8 = t >> 3, chunk8 = (t & 7) * 8;
    int vd = t >> 2, vch = (t & 3) * 8;
    for (int kt = 0; kt <= qhi; ++kt) {
#pragma unroll
        for (int i = 0; i < 2; ++i) {
            int sr = i * 32 + srow8;
            *(uint4*)&Ks[sr][chunk8] =
                *(const uint4*)(qkb + (size_t)(kt * 64 + sr) * 2048 + 64 + chunk8);
        }
        {
            const unsigned short* vsrc = vtb + (size_t)vd * 2048 + kt * 64;
            *(uint4*)&Vts[vd][vch] = *(const uint4*)(vsrc + vch);
            *(uint4*)&Vts[vd][vch + 32] = *(const uint4*)(vsrc + vch + 32);
        }
        __syncthreads();
        attn_tile(oh, mh, lh, qfh, Ks, Vts, Ps[wave], kt == qhi, wave, l15, quad);
        if (kt <= qlo)
            attn_tile(ol, ml, ll, qfl, Ks, Vts, Ps[wave], kt == qlo, wave, l15, quad);
        __syncthreads();
    }
    unsigned short* ob = out + (size_t)b * S * 1024 + h * 64;
    attn_store(ob, ol, ll, qlo, wave, l15, quad);
    attn_store(ob, oh, lh, qhi, wave, l15, quad);
}

// ----------------------------------------------------------------
extern "C" void kernel_launch(void* const* d_in, const int* in_sizes, int n_in,
                              void* d_out, int out_size, void* d_ws, size_t ws_size,
                              hipStream_t stream) {
    const float* hs     = (const float*)d_in[0];
    const float* W_attn = (const float*)d_in[1];
    const float* b_attn = (const float*)d_in[2];
    const float* W_proj = (const float*)d_in[3];
    const float* b_proj = (const float*)d_in[4];
    float* out = (float*)d_out;

    const int B = 2, S = 2048, E = 1024;
    const int M = B * S;        // 4096
    const int N3 = 3 * E;       // 3072

    unsigned short* Xb  = (unsigned short*)d_ws;          // M*E
    unsigned short* WaT = Xb + (size_t)M * E;             // N3*E
    unsigned short* WpT = WaT + (size_t)N3 * E;           // E*E
    unsigned short* qkb = WpT + (size_t)E * E;            // M*2048
    unsigned short* Vt  = qkb + (size_t)M * 2048;         // M*E (=B*H*64*S)
    unsigned short* ao  = Vt + (size_t)M * E;             // M*E

    cast_f32_bf16<<<(M * E) / 1024, 256, 0, stream>>>(hs, Xb, M * E);
    transpose_w<<<dim3(N3 / 32, E / 32), 256, 0, stream>>>(W_attn, WaT, E, N3);
    transpose_w<<<dim3(E / 32, E / 32), 256, 0, stream>>>(W_proj, WpT, E, E);

    gemm128<1><<<dim3(N3 / 128, M / 128), 256, 0, stream>>>(Xb, WaT, b_attn, qkb, Vt, M, N3, E);

    attn2<<<dim3(B * 16 * 16), 256, 0, stream>>>(qkb, Vt, ao);

    gemm128<0><<<dim3(E / 128, M / 128), 256, 0, stream>>>(ao, WpT, b_proj, out, nullptr, M, E, E);
}

// Round 4
// 210.712 us; speedup vs baseline: 1.6294x; 1.0325x over previous
//
#include <hip/hip_runtime.h>
#include <hip/hip_bf16.h>

// GPT2 attention, B=2 S=2048 E=1024 H=16 hd=64.
// cast X->bf16; transpose weights->bf16 [N][K]; m97-style MFMA GEMM qkv
// (V written transposed to Vt[b][h][d][s]); UNPAIRED flash attention
// (grid 1024, one q-tile per block, big tiles first, round-2 math);
// m97-style MFMA GEMM proj -> fp32 out.

typedef __attribute__((ext_vector_type(4))) float f32x4;
typedef __attribute__((ext_vector_type(8))) short short8;

#define AS1 __attribute__((address_space(1)))
#define AS3 __attribute__((address_space(3)))

__device__ __forceinline__ void load_lds16(const void* g, void* l) {
    __builtin_amdgcn_global_load_lds((const AS1 void*)g, (AS3 void*)l, 16, 0, 0);
}

__device__ __forceinline__ unsigned short f2bf(float f) {       // RNE
    union { float f; unsigned int u; } v; v.f = f;
    unsigned int r = v.u + 0x7FFFu + ((v.u >> 16) & 1u);
    return (unsigned short)(r >> 16);
}

template <int CTRL>
__device__ __forceinline__ float rot_add(float x) {
    int r = __builtin_amdgcn_update_dpp(0, __builtin_bit_cast(int, x), CTRL, 0xF, 0xF, false);
    return x + __builtin_bit_cast(float, r);
}
template <int CTRL>
__device__ __forceinline__ float rot_max(float x) {
    int r = __builtin_amdgcn_update_dpp(0, __builtin_bit_cast(int, x), CTRL, 0xF, 0xF, false);
    return fmaxf(x, __builtin_bit_cast(float, r));
}

// ---------------------------------------------------------------- cast fp32 -> bf16
__global__ __launch_bounds__(256) void cast_f32_bf16(
    const float* __restrict__ in, unsigned short* __restrict__ out, int n) {
    int i = (blockIdx.x * 256 + threadIdx.x) * 4;
    if (i >= n) return;
    float4 v = *(const float4*)(in + i);
    ushort4 o;
    o.x = f2bf(v.x); o.y = f2bf(v.y); o.z = f2bf(v.z); o.w = f2bf(v.w);
    *(ushort4*)(out + i) = o;
}

// ---------------------------------------------------------------- W [K][N] fp32 -> Wt [N][K] bf16
__global__ __launch_bounds__(256) void transpose_w(
    const float* __restrict__ W, unsigned short* __restrict__ Wt, int K, int N) {
    __shared__ float tile[32][33];
    int k0 = blockIdx.y * 32, n0 = blockIdx.x * 32;
    int t = threadIdx.x;
    int r = t >> 3, c = (t & 7) * 4;
    float4 v = *(const float4*)&W[(size_t)(k0 + r) * N + n0 + c];
    tile[r][c] = v.x; tile[r][c + 1] = v.y; tile[r][c + 2] = v.z; tile[r][c + 3] = v.w;
    __syncthreads();
    int n = t >> 3; int kk = (t & 7) * 4;
    ushort4 o;
    o.x = f2bf(tile[kk + 0][n]);
    o.y = f2bf(tile[kk + 1][n]);
    o.z = f2bf(tile[kk + 2][n]);
    o.w = f2bf(tile[kk + 3][n]);
    *(ushort4*)&Wt[(size_t)(n0 + n) * K + k0 + kk] = o;
}

// ---------------------------------------------------------------- m97-style GEMM
// C[M][N] = A[M][K] @ Bt[N][K]^T + bias. 128x128 tile, BK=32, 4 waves 2x2.
// MODE 0: fp32 C. MODE 1: qkv split -> qk[s][h*128 + (q|k)] bf16, V -> Vt[b][h][d][s].
template <int MODE>
__global__ __launch_bounds__(256) void gemm128(
    const unsigned short* __restrict__ A,
    const unsigned short* __restrict__ Bt,
    const float* __restrict__ bias,
    void* __restrict__ C, unsigned short* __restrict__ Vt,
    int M, int N, int K) {
    __shared__ unsigned short As[128 * 32];
    __shared__ unsigned short Bs[128 * 32];
    const int t = threadIdx.x, wave = t >> 6, lane = t & 63;
    const int l15 = lane & 15, quad = lane >> 4;
    const int m0 = blockIdx.y * 128, n0 = blockIdx.x * 128;
    const int srow = wave * 32 + (lane >> 2);
    const int sch = (lane & 3) * 8;
    const unsigned short* Ag = A + (size_t)(m0 + srow) * K + sch;
    const unsigned short* Bg = Bt + (size_t)(n0 + srow) * K + sch;
    unsigned short* AsW = &As[wave * 32 * 32];
    unsigned short* BsW = &Bs[wave * 32 * 32];
    const int wm = (wave >> 1) * 64, wn = (wave & 1) * 64;
    f32x4 acc[4][4] = {};
    for (int k0 = 0; k0 < K; k0 += 32) {
        load_lds16(Ag + k0, AsW);
        load_lds16(Ag + k0 + (size_t)16 * K, AsW + 16 * 32);
        load_lds16(Bg + k0, BsW);
        load_lds16(Bg + k0 + (size_t)16 * K, BsW + 16 * 32);
        __syncthreads();
        short8 af[4], bf[4];
#pragma unroll
        for (int i = 0; i < 4; ++i) {
            af[i] = *(const short8*)&As[(wm + i * 16 + l15) * 32 + quad * 8];
            bf[i] = *(const short8*)&Bs[(wn + i * 16 + l15) * 32 + quad * 8];
        }
#pragma unroll
        for (int mt = 0; mt < 4; ++mt)
#pragma unroll
            for (int nt = 0; nt < 4; ++nt)
                acc[mt][nt] = __builtin_amdgcn_mfma_f32_16x16x32_bf16(af[mt], bf[nt], acc[mt][nt], 0, 0, 0);
        __syncthreads();
    }
#pragma unroll
    for (int mt = 0; mt < 4; ++mt) {
        int mrow = m0 + wm + mt * 16 + quad * 4;
#pragma unroll
        for (int nt = 0; nt < 4; ++nt) {
            int col = n0 + wn + nt * 16 + l15;
            float bv = bias[col];
            if (MODE == 0) {
                float* Cf = (float*)C;
#pragma unroll
                for (int r = 0; r < 4; ++r)
                    Cf[(size_t)(mrow + r) * N + col] = acc[mt][nt][r] + bv;
            } else {
                int h = col / 192;
                int j = col - h * 192;
                if (j < 128) {  // Q or K -> qk buffer (both land at h*128 + j)
                    unsigned short* qk = (unsigned short*)C;
#pragma unroll
                    for (int r = 0; r < 4; ++r)
                        qk[(size_t)(mrow + r) * 2048 + h * 128 + j] = f2bf(acc[mt][nt][r] + bv);
                } else {        // V -> Vt[b][h][d][s], 4 consecutive s packed
                    int b = mrow >> 11, s0 = mrow & 2047;
                    int d = j - 128;
                    ushort4 pk;
                    pk.x = f2bf(acc[mt][nt][0] + bv);
                    pk.y = f2bf(acc[mt][nt][1] + bv);
                    pk.z = f2bf(acc[mt][nt][2] + bv);
                    pk.w = f2bf(acc[mt][nt][3] + bv);
                    *(ushort4*)&Vt[((size_t)(b * 16 + h) * 64 + d) * 2048 + s0] = pk;
                }
            }
        }
    }
}

// ---------------------------------------------------------------- flash attention tile
// Round-2 math: scale 0.125 in-tile, mask -10000, __expf, RNE pack.
__device__ __forceinline__ void attn_tile(
    f32x4 (&o)[4], float (&mrun)[4], float (&lrun)[4],
    const short8 (&qf)[2],
    const unsigned short (*Ks)[72], const unsigned short (*Vts)[72],
    unsigned short (*Psw)[72],
    bool diag, int wave, int l15, int quad) {
    f32x4 s[4] = {};
#pragma unroll
    for (int km = 0; km < 2; ++km)
#pragma unroll
        for (int nt = 0; nt < 4; ++nt) {
            short8 kf = *(const short8*)&Ks[nt * 16 + l15][km * 32 + quad * 8];
            s[nt] = __builtin_amdgcn_mfma_f32_16x16x32_bf16(qf[km], kf, s[nt], 0, 0, 0);
        }
#pragma unroll
    for (int nt = 0; nt < 4; ++nt)
#pragma unroll
        for (int r = 0; r < 4; ++r) {
            float v = s[nt][r] * 0.125f;
            if (diag && (nt * 16 + l15 > wave * 16 + quad * 4 + r)) v = -10000.0f;
            s[nt][r] = v;
        }
#pragma unroll
    for (int r = 0; r < 4; ++r) {
        float v = fmaxf(fmaxf(s[0][r], s[1][r]), fmaxf(s[2][r], s[3][r]));
        v = rot_max<0x121>(v); v = rot_max<0x122>(v);
        v = rot_max<0x124>(v); v = rot_max<0x128>(v);
        float mnew = fmaxf(mrun[r], v);
        float alpha = __expf(mrun[r] - mnew);
        mrun[r] = mnew;
        float lt = 0.f;
#pragma unroll
        for (int nt = 0; nt < 4; ++nt) {
            float pv = __expf(s[nt][r] - mnew);
            s[nt][r] = pv;
            lt += pv;
        }
        lt = rot_add<0x121>(lt); lt = rot_add<0x122>(lt);
        lt = rot_add<0x124>(lt); lt = rot_add<0x128>(lt);
        lrun[r] = lrun[r] * alpha + lt;
#pragma unroll
        for (int nt = 0; nt < 4; ++nt) o[nt][r] *= alpha;
    }
    // P: C-layout -> A-layout via wave-private LDS (per-wave in-order, no barrier)
#pragma unroll
    for (int nt = 0; nt < 4; ++nt)
#pragma unroll
        for (int r = 0; r < 4; ++r)
            Psw[quad * 4 + r][nt * 16 + l15] = f2bf(s[nt][r]);
#pragma unroll
    for (int km = 0; km < 2; ++km) {
        short8 pf = *(const short8*)&Psw[l15][km * 32 + quad * 8];
#pragma unroll
        for (int nt = 0; nt < 4; ++nt) {
            short8 vf = *(const short8*)&Vts[nt * 16 + l15][km * 32 + quad * 8];
            o[nt] = __builtin_amdgcn_mfma_f32_16x16x32_bf16(pf, vf, o[nt], 0, 0, 0);
        }
    }
}

// One block per (b, h, q-tile); largest trip counts dispatched first.
__global__ __launch_bounds__(256) void attn1(
    const unsigned short* __restrict__ qk,   // [B*S][2048], head h: [h*128+q | +64 k]
    const unsigned short* __restrict__ Vt,   // [B*H][64][2048]
    unsigned short* __restrict__ out) {      // [B*S][1024]
    const int S = 2048;
    __shared__ unsigned short Ks[64][72];
    __shared__ unsigned short Vts[64][72];
    __shared__ unsigned short Ps[4][16][72];
    int t = threadIdx.x, wave = t >> 6, lane = t & 63;
    int l15 = lane & 15, quad = lane >> 4;
    int bid = blockIdx.x;
    int qt = 31 - (bid >> 5);      // big tiles first
    int bh = bid & 31;
    int b = bh >> 4, h = bh & 15;
    const unsigned short* qkb = qk + (size_t)b * S * 2048 + h * 128;
    const unsigned short* vtb = Vt + (size_t)bh * 64 * 2048;

    short8 qf[2];
    {
        int qr = qt * 64 + wave * 16 + l15;
#pragma unroll
        for (int km = 0; km < 2; ++km)
            qf[km] = *(const short8*)(qkb + (size_t)qr * 2048 + km * 32 + quad * 8);
    }
    f32x4 o[4] = {};
    float mrun[4], lrun[4];
#pragma unroll
    for (int r = 0; r < 4; ++r) { mrun[r] = -1e30f; lrun[r] = 0.f; }

    int srow8 = t >> 3, chunk8 = (t & 7) * 8;
    int vd = t >> 2, vch = (t & 3) * 8;
    for (int kt = 0; kt <= qt; ++kt) {
#pragma unroll
        for (int i = 0; i < 2; ++i) {
            int sr = i * 32 + srow8;
            *(uint4*)&Ks[sr][chunk8] =
                *(const uint4*)(qkb + (size_t)(kt * 64 + sr) * 2048 + 64 + chunk8);
        }
        {
            const unsigned short* vsrc = vtb + (size_t)vd * 2048 + kt * 64;
            *(uint4*)&Vts[vd][vch] = *(const uint4*)(vsrc + vch);
            *(uint4*)&Vts[vd][vch + 32] = *(const uint4*)(vsrc + vch + 32);
        }
        __syncthreads();
        attn_tile(o, mrun, lrun, qf, Ks, Vts, Ps[wave], kt == qt, wave, l15, quad);
        __syncthreads();
    }
    unsigned short* ob = out + (size_t)b * S * 1024 + h * 64;
#pragma unroll
    for (int r = 0; r < 4; ++r) {
        float inv = 1.0f / lrun[r];
        int srow = qt * 64 + wave * 16 + quad * 4 + r;
#pragma unroll
        for (int nt = 0; nt < 4; ++nt)
            ob[(size_t)srow * 1024 + nt * 16 + l15] = f2bf(o[nt][r] * inv);
    }
}

// ----------------------------------------------------------------
extern "C" void kernel_launch(void* const* d_in, const int* in_sizes, int n_in,
                              void* d_out, int out_size, void* d_ws, size_t ws_size,
                              hipStream_t stream) {
    const float* hs     = (const float*)d_in[0];
    const float* W_attn = (const float*)d_in[1];
    const float* b_attn = (const float*)d_in[2];
    const float* W_proj = (const float*)d_in[3];
    const float* b_proj = (const float*)d_in[4];
    float* out = (float*)d_out;

    const int B = 2, S = 2048, E = 1024;
    const int M = B * S;        // 4096
    const int N3 = 3 * E;       // 3072

    unsigned short* Xb  = (unsigned short*)d_ws;          // M*E
    unsigned short* WaT = Xb + (size_t)M * E;             // N3*E
    unsigned short* WpT = WaT + (size_t)N3 * E;           // E*E
    unsigned short* qkb = WpT + (size_t)E * E;            // M*2048
    unsigned short* Vt  = qkb + (size_t)M * 2048;         // M*E
    unsigned short* ao  = Vt + (size_t)M * E;             // M*E

    cast_f32_bf16<<<(M * E) / 1024, 256, 0, stream>>>(hs, Xb, M * E);
    transpose_w<<<dim3(N3 / 32, E / 32), 256, 0, stream>>>(W_attn, WaT, E, N3);
    transpose_w<<<dim3(E / 32, E / 32), 256, 0, stream>>>(W_proj, WpT, E, E);

    gemm128<1><<<dim3(N3 / 128, M / 128), 256, 0, stream>>>(Xb, WaT, b_attn, qkb, Vt, M, N3, E);

    attn1<<<dim3(32 * 32), 256, 0, stream>>>(qkb, Vt, ao);

    gemm128<0><<<dim3(E / 128, M / 128), 256, 0, stream>>>(ao, WpT, b_proj, out, nullptr, M, E, E);
}